// Round 1
// 295.429 us; speedup vs baseline: 1.1061x; 1.1061x over previous
//
#include <hip/hip_runtime.h>

typedef unsigned short u16;
typedef __attribute__((ext_vector_type(8))) short bf16x8;
typedef __attribute__((ext_vector_type(4))) float f32x4;
typedef __attribute__((ext_vector_type(4))) unsigned short u16x4;
typedef __attribute__((ext_vector_type(8))) unsigned short u16x8;

#define MFMA16(a, b, c) __builtin_amdgcn_mfma_f32_16x16x32_bf16((a), (b), (c), 0, 0, 0)

// d_ws layout (u16 element offsets). All operands PRE-PACKED in per-wave
// fragment order so every B-load in k_fused is a wave-contiguous 1KB burst:
//   dense W (256-out): elem (((w*8+kk)*2+nt)*64+lane)*8+j  <- W[w*32+nt*16+l16][kk*32+quad*8+j]
//   Wc1  (128-out):    elem ((w*8+kk)*64+lane)*8+j         <- Wc1[w*16+l16][kk*32+quad*8+j]
//   KN   (per head):   elem (((h*2+kk)*4+nt)*64+lane)*8+j  <- KN[h][nt*16+l16][kk*32+quad*8+j]
//   VT   (per head):   elem (((h*2+kk)*4+nt)*64+lane)*8+j  <- V [h][kk*32+quad*8+j][nt*16+l16]
#define OFF_WQ   0
#define OFF_WG   65536
#define OFF_WC1  131072
#define OFF_WO   163840
#define OFF_KNF  229376
#define OFF_VTF  245760
#define OFF_KND  262144
#define OFF_VTD  278528

__device__ __forceinline__ u16 f2b(float f) {
  union { float f; unsigned u; } v; v.f = f;
  unsigned r = v.u + 0x7fffu + ((v.u >> 16) & 1u);  // RNE fp32->bf16
  return (u16)(r >> 16);
}
__device__ __forceinline__ float fsig(float x) {
  return __builtin_amdgcn_rcpf(1.f + __expf(-x));
}
__device__ __forceinline__ float ftanh(float x) {
  float e = __expf(2.f * x);
  return (e - 1.f) * __builtin_amdgcn_rcpf(e + 1.f);
}
__device__ __forceinline__ float sum16(float v) {
  v += __shfl_xor(v, 1);
  v += __shfl_xor(v, 2);
  v += __shfl_xor(v, 4);
  v += __shfl_xor(v, 8);
  return v;
}

// ---------- single pre-kernel: convert+pack weights, norm/pack keys, transpose/pack vals ----------
__global__ void k_prep(const float* __restrict__ Wq, const float* __restrict__ Wg,
                       const float* __restrict__ Wc1, const float* __restrict__ Wo,
                       const float* __restrict__ fk, const float* __restrict__ fv,
                       const float* __restrict__ dk, const float* __restrict__ dv,
                       u16* __restrict__ ws) {
  const int bid = blockIdx.x, t = threadIdx.x;
  if (bid < 96) {  // Wq/Wg/Wo: 8192 16B-chunks each, 32 blocks each
    const float* W = bid < 32 ? Wq : (bid < 64 ? Wg : Wo);
    const int OFF = bid < 32 ? OFF_WQ : (bid < 64 ? OFF_WG : OFF_WO);
    int c = (bid & 31) * 256 + t;
    int lane = c & 63, nt = (c >> 6) & 1, kk = (c >> 7) & 7, w = c >> 10;
    const float* s = W + (w * 32 + nt * 16 + (lane & 15)) * 256 + kk * 32 + ((lane >> 4) & 3) * 8;
    u16x8 o;
    #pragma unroll
    for (int j = 0; j < 8; ++j) o[j] = f2b(s[j]);
    *(u16x8*)(ws + OFF + c * 8) = o;
  } else if (bid < 112) {  // Wc1: 4096 chunks, 16 blocks
    int c = (bid - 96) * 256 + t;
    int lane = c & 63, kk = (c >> 6) & 7, w = c >> 9;
    const float* s = Wc1 + (w * 16 + (lane & 15)) * 256 + kk * 32 + ((lane >> 4) & 3) * 8;
    u16x8 o;
    #pragma unroll
    for (int j = 0; j < 8; ++j) o[j] = f2b(s[j]);
    *(u16x8*)(ws + OFF_WC1 + c * 8) = o;
  } else {  // keys/vals: 4 structures x 256 rows, 4 blocks
    int idx = (bid - 112) * 256 + t;
    int st = idx >> 8, rowid = idx & 255;
    int h = rowid >> 6, s = rowid & 63;
    if (st < 2) {  // keys: normalize then scatter into packed B-layout
      const float* p = (st == 0 ? fk : dk) + rowid * 64;
      const int OFF = (st == 0) ? OFF_KNF : OFF_KND;
      float ss = 0.f;
      #pragma unroll
      for (int d = 0; d < 64; ++d) { float x = p[d]; ss += x * x; }
      float sc = __builtin_amdgcn_rcpf(__builtin_amdgcn_sqrtf(ss) + 1e-8f);
      int nt = s >> 4, sl = s & 15;
      #pragma unroll
      for (int d = 0; d < 64; ++d) {
        int lane = ((d >> 3) & 3) * 16 + sl;
        ws[OFF + (((h * 2 + (d >> 5)) * 4 + nt) * 64 + lane) * 8 + (d & 7)] = f2b(p[d] * sc);
      }
    } else {  // vals: transpose into packed B-layout
      const float* p = (st == 2 ? fv : dv) + rowid * 64;
      const int OFF = (st == 2) ? OFF_VTF : OFF_VTD;
      int kk = s >> 5, quad = (s >> 3) & 3, j = s & 7;
      #pragma unroll
      for (int d = 0; d < 64; ++d) {
        int lane = quad * 16 + (d & 15);
        ws[OFF + (((h * 2 + kk) * 4 + (d >> 4)) * 64 + lane) * 8 + j] = f2b(p[d]);
      }
    }
  }
}

// ---------- fused main kernel ----------
// 1024 blocks x 512 threads (8 waves); 64 rows/block.
// Dense GEMMs: wave w owns output cols [w*32, w*32+32).
// Attention: wave w owns head h=w>>1, q-rows rh=(w&1)*32 .. rh+31.
// Register budget target: <=128 VGPR+AGPR -> 4 waves/SIMD (2 blocks/CU).
__global__ __launch_bounds__(512, 4)
void k_fused(const float* __restrict__ query, const float* __restrict__ context,
             const float* __restrict__ bq, const float* __restrict__ bg,
             const float* __restrict__ bc1, const float* __restrict__ Wc2,
             const float* __restrict__ bc2v, const float* __restrict__ bo,
             const float* __restrict__ mixl, const u16* __restrict__ ws,
             float* __restrict__ outp) {
  __shared__ u16 sX[64 * 256];      // 32 KB: ctx -> query -> (chunks: q,P) -> out_pre
  __shared__ float red_a[8][64];    // gate partials, then q-norm ss partials
  __shared__ float red_c[8][64];    // conf partials
  __shared__ float sA[64];          // conf*mix
  __shared__ float sB[64];          // conf*(1-mix)

  const int t = threadIdx.x;
  const int w = t >> 6;
  const int lane = t & 63;
  const int quad = lane >> 4;
  const int l16 = lane & 15;
  const int row4 = quad * 4;
  const int h = w >> 1;             // attention head
  const int rh = (w & 1) * 32;      // attention row-half
  const int blk = blockIdx.x;
  char* Xb = (char*)sX;
  char* Ch = Xb + h * 8192;         // per-head 64x64 bf16 chunk (q then P), swizzled

  auto stage = [&](const float* src) {
    #pragma unroll
    for (int i = 0; i < 8; ++i) {
      int e = i * 2048 + t * 4;
      float4 v = *(const float4*)(src + e);
      int row = e >> 8, col = e & 255;
      u16x4 pk;
      pk.x = f2b(v.x); pk.y = f2b(v.y); pk.z = f2b(v.z); pk.w = f2b(v.w);
      *(u16x4*)(Xb + row * 512 + ((((col >> 3) ^ (row & 7)) << 4) | ((col & 7) << 1))) = pk;
    }
  };
  auto ldA = [&](int row, int kb) {  // A-frag from X: m=row, k=kb..kb+7
    return *(const bf16x8*)(Xb + row * 512 + ((((kb >> 3) ^ (row & 7)) << 4)));
  };
  auto ldC = [&](int row, int kb) {  // A-frag from head chunk
    return *(const bf16x8*)(Ch + row * 128 + ((((kb >> 3) ^ (row & 7)) << 4)));
  };
  auto cwr = [&](int row, int col, u16 v) {  // scalar bf16 write into head chunk
    *(u16*)(Ch + row * 128 + (((((col >> 3) ^ (row & 7)) << 3) | (col & 7)) << 1)) = v;
  };

  const f32x4 vzero = {0.f, 0.f, 0.f, 0.f};

  // ===== Phase 1: stage context; hoist small params =====
  stage(context + (size_t)blk * 16384);
  float bgv[2], bqv[2], bov[2];
  #pragma unroll
  for (int nt = 0; nt < 2; ++nt) {
    int n = w * 32 + nt * 16 + l16;
    bgv[nt] = bg[n]; bqv[nt] = bq[n]; bov[nt] = bo[n];
  }
  float bc1v = bc1[w * 16 + l16];
  float wc2v = Wc2[w * 16 + l16];
  __syncthreads();  // bar1: ctx staged

  // ===== gate + conf GEMMs (shared A-frags) =====
  {
    f32x4 ag[4][2], ac[4];
    #pragma unroll
    for (int mt = 0; mt < 4; ++mt) { ag[mt][0] = vzero; ag[mt][1] = vzero; ac[mt] = vzero; }
    #pragma unroll
    for (int kk = 0; kk < 8; ++kk) {
      int kb = kk * 32 + quad * 8;
      bf16x8 a0 = ldA(l16, kb), a1 = ldA(16 + l16, kb), a2 = ldA(32 + l16, kb), a3 = ldA(48 + l16, kb);
      #pragma unroll
      for (int nt = 0; nt < 2; ++nt) {
        bf16x8 b = *(const bf16x8*)(ws + OFF_WG + (((w * 8 + kk) * 2 + nt) * 64 + lane) * 8);
        ag[0][nt] = MFMA16(a0, b, ag[0][nt]);
        ag[1][nt] = MFMA16(a1, b, ag[1][nt]);
        ag[2][nt] = MFMA16(a2, b, ag[2][nt]);
        ag[3][nt] = MFMA16(a3, b, ag[3][nt]);
      }
      bf16x8 bc = *(const bf16x8*)(ws + OFF_WC1 + ((w * 8 + kk) * 64 + lane) * 8);
      ac[0] = MFMA16(a0, bc, ac[0]);
      ac[1] = MFMA16(a1, bc, ac[1]);
      ac[2] = MFMA16(a2, bc, ac[2]);
      ac[3] = MFMA16(a3, bc, ac[3]);
    }
    #pragma unroll
    for (int mt = 0; mt < 4; ++mt)
      #pragma unroll
      for (int r = 0; r < 4; ++r) {
        float sg = ftanh(ag[mt][0][r] + bgv[0]) + ftanh(ag[mt][1][r] + bgv[1]);
        sg = sum16(sg);
        float sc = ftanh(ac[mt][r] + bc1v) * wc2v;
        sc = sum16(sc);
        if (l16 == 0) { red_a[w][mt * 16 + row4 + r] = sg; red_c[w][mt * 16 + row4 + r] = sc; }
      }
  }
  __syncthreads();  // bar2: partials ready, X reads done

  // ===== combine partials; stage query (overwrites X) =====
  if (t < 64) {
    float g = 0.f, cc = 0.f;
    #pragma unroll
    for (int i = 0; i < 8; ++i) { g += red_a[i][t]; cc += red_c[i][t]; }
    float mix = fsig(mixl[0] + g * (1.f / 256.f));
    float conf = fsig(cc + bc2v[0]);
    sA[t] = conf * mix;
    sB[t] = conf - conf * mix;
  }
  stage(query + (size_t)blk * 16384);
  __syncthreads();  // bar3: query staged + sA/sB ready

  // ===== Wq GEMM + per-head q-norm partials =====
  f32x4 qa[4][2];
  {
    #pragma unroll
    for (int mt = 0; mt < 4; ++mt) { qa[mt][0] = vzero; qa[mt][1] = vzero; }
    #pragma unroll
    for (int kk = 0; kk < 8; ++kk) {
      int kb = kk * 32 + quad * 8;
      bf16x8 a0 = ldA(l16, kb), a1 = ldA(16 + l16, kb), a2 = ldA(32 + l16, kb), a3 = ldA(48 + l16, kb);
      #pragma unroll
      for (int nt = 0; nt < 2; ++nt) {
        bf16x8 b = *(const bf16x8*)(ws + OFF_WQ + (((w * 8 + kk) * 2 + nt) * 64 + lane) * 8);
        qa[0][nt] = MFMA16(a0, b, qa[0][nt]);
        qa[1][nt] = MFMA16(a1, b, qa[1][nt]);
        qa[2][nt] = MFMA16(a2, b, qa[2][nt]);
        qa[3][nt] = MFMA16(a3, b, qa[3][nt]);
      }
    }
    #pragma unroll
    for (int mt = 0; mt < 4; ++mt)
      #pragma unroll
      for (int r = 0; r < 4; ++r) {
        float ss = 0.f;
        #pragma unroll
        for (int nt = 0; nt < 2; ++nt) {
          float q_ = qa[mt][nt][r] + bqv[nt];
          qa[mt][nt][r] = q_;
          ss += q_ * q_;
        }
        ss = sum16(ss);
        if (l16 == 0) red_a[w][mt * 16 + row4 + r] = ss;
      }
  }
  __syncthreads();  // bar4: ss partials ready, all X reads done (chunks may overwrite X)

  // write normalized q (bf16) into head chunk: wave w fills d-cols (w&1)*32..+31, all 64 rows
  #pragma unroll
  for (int mt = 0; mt < 4; ++mt)
    #pragma unroll
    for (int r = 0; r < 4; ++r) {
      int row = mt * 16 + row4 + r;
      float ss = red_a[w][row] + red_a[w ^ 1][row];
      float scl = __builtin_amdgcn_rcpf(__builtin_amdgcn_sqrtf(ss) + 1e-8f);
      #pragma unroll
      for (int nt = 0; nt < 2; ++nt)
        cwr(row, (w & 1) * 32 + nt * 16 + l16, f2b(qa[mt][nt][r] * scl));
    }
  __syncthreads();  // bar5: both waves of each head done writing q

  // ===== attention: wave-local from here (no barriers) =====
  bf16x8 qf[2][2];  // q A-frags held in regs across BOTH tiers
  #pragma unroll
  for (int mt = 0; mt < 2; ++mt)
    #pragma unroll
    for (int kk = 0; kk < 2; ++kk)
      qf[mt][kk] = ldC(rh + mt * 16 + l16, kk * 32 + quad * 8);

  f32x4 sf[2][4], sd[2][4];
  #pragma unroll
  for (int mt = 0; mt < 2; ++mt)
    #pragma unroll
    for (int nt = 0; nt < 4; ++nt) { sf[mt][nt] = vzero; sd[mt][nt] = vzero; }
  #pragma unroll
  for (int kk = 0; kk < 2; ++kk)
    #pragma unroll
    for (int nt = 0; nt < 4; ++nt) {
      bf16x8 bF = *(const bf16x8*)(ws + OFF_KNF + (((h * 2 + kk) * 4 + nt) * 64 + lane) * 8);
      bf16x8 bD = *(const bf16x8*)(ws + OFF_KND + (((h * 2 + kk) * 4 + nt) * 64 + lane) * 8);
      sf[0][nt] = MFMA16(qf[0][kk], bF, sf[0][nt]);
      sf[1][nt] = MFMA16(qf[1][kk], bF, sf[1][nt]);
      sd[0][nt] = MFMA16(qf[0][kk], bD, sd[0][nt]);
      sd[1][nt] = MFMA16(qf[1][kk], bD, sd[1][nt]);
    }

  f32x4 oacc[2][4];
  {  // ---- fast tier: softmax (cos sims bounded by 1) + PV ----
    #pragma unroll
    for (int mt = 0; mt < 2; ++mt)
      #pragma unroll
      for (int r = 0; r < 4; ++r) {
        float rs = 0.f;
        #pragma unroll
        for (int nt = 0; nt < 4; ++nt) { float e = __expf(sf[mt][nt][r]); sf[mt][nt][r] = e; rs += e; }
        rs = sum16(rs);
        float inv = __builtin_amdgcn_rcpf(rs);
        int row = rh + mt * 16 + row4 + r;
        #pragma unroll
        for (int nt = 0; nt < 4; ++nt) cwr(row, nt * 16 + l16, f2b(sf[mt][nt][r] * inv));
      }
    bf16x8 pf00 = ldC(rh + l16, quad * 8),      pf01 = ldC(rh + l16, 32 + quad * 8);
    bf16x8 pf10 = ldC(rh + 16 + l16, quad * 8), pf11 = ldC(rh + 16 + l16, 32 + quad * 8);
    f32x4 pv[2][4];
    #pragma unroll
    for (int mt = 0; mt < 2; ++mt)
      #pragma unroll
      for (int nt = 0; nt < 4; ++nt) pv[mt][nt] = vzero;
    #pragma unroll
    for (int kk = 0; kk < 2; ++kk)
      #pragma unroll
      for (int nt = 0; nt < 4; ++nt) {
        bf16x8 b = *(const bf16x8*)(ws + OFF_VTF + (((h * 2 + kk) * 4 + nt) * 64 + lane) * 8);
        pv[0][nt] = MFMA16(kk ? pf01 : pf00, b, pv[0][nt]);
        pv[1][nt] = MFMA16(kk ? pf11 : pf10, b, pv[1][nt]);
      }
    #pragma unroll
    for (int mt = 0; mt < 2; ++mt)
      #pragma unroll
      for (int r = 0; r < 4; ++r) {
        float m_ = sA[rh + mt * 16 + row4 + r];
        #pragma unroll
        for (int nt = 0; nt < 4; ++nt) oacc[mt][nt][r] = m_ * pv[mt][nt][r];
      }
  }
  {  // ---- deep tier ----
    #pragma unroll
    for (int mt = 0; mt < 2; ++mt)
      #pragma unroll
      for (int r = 0; r < 4; ++r) {
        float rs = 0.f;
        #pragma unroll
        for (int nt = 0; nt < 4; ++nt) { float e = __expf(sd[mt][nt][r]); sd[mt][nt][r] = e; rs += e; }
        rs = sum16(rs);
        float inv = __builtin_amdgcn_rcpf(rs);
        int row = rh + mt * 16 + row4 + r;
        #pragma unroll
        for (int nt = 0; nt < 4; ++nt) cwr(row, nt * 16 + l16, f2b(sd[mt][nt][r] * inv));
      }
    bf16x8 pf00 = ldC(rh + l16, quad * 8),      pf01 = ldC(rh + l16, 32 + quad * 8);
    bf16x8 pf10 = ldC(rh + 16 + l16, quad * 8), pf11 = ldC(rh + 16 + l16, 32 + quad * 8);
    f32x4 pv[2][4];
    #pragma unroll
    for (int mt = 0; mt < 2; ++mt)
      #pragma unroll
      for (int nt = 0; nt < 4; ++nt) pv[mt][nt] = vzero;
    #pragma unroll
    for (int kk = 0; kk < 2; ++kk)
      #pragma unroll
      for (int nt = 0; nt < 4; ++nt) {
        bf16x8 b = *(const bf16x8*)(ws + OFF_VTD + (((h * 2 + kk) * 4 + nt) * 64 + lane) * 8);
        pv[0][nt] = MFMA16(kk ? pf01 : pf00, b, pv[0][nt]);
        pv[1][nt] = MFMA16(kk ? pf11 : pf10, b, pv[1][nt]);
      }
    #pragma unroll
    for (int mt = 0; mt < 2; ++mt)
      #pragma unroll
      for (int r = 0; r < 4; ++r) {
        float m_ = sB[rh + mt * 16 + row4 + r];
        #pragma unroll
        for (int nt = 0; nt < 4; ++nt) oacc[mt][nt][r] += m_ * pv[mt][nt][r];
      }
  }

  // ===== Phase 3: out_pre -> X, final GEMM (Wo) =====
  __syncthreads();  // bar6: all chunk reads done before X reused as out_pre
  #pragma unroll
  for (int mt = 0; mt < 2; ++mt)
    #pragma unroll
    for (int r = 0; r < 4; ++r) {
      int row = rh + mt * 16 + row4 + r;
      #pragma unroll
      for (int nt = 0; nt < 4; ++nt) {
        int col = h * 64 + nt * 16 + l16;
        *(u16*)(Xb + row * 512 + ((((col >> 3) ^ (row & 7)) << 4) | ((col & 7) << 1))) =
            f2b(oacc[mt][nt][r]);
      }
    }
  __syncthreads();  // bar7: out_pre complete

  {
    f32x4 o[4][2];
    #pragma unroll
    for (int mt = 0; mt < 4; ++mt) { o[mt][0] = vzero; o[mt][1] = vzero; }
    #pragma unroll
    for (int kk = 0; kk < 8; ++kk) {
      int kb = kk * 32 + quad * 8;
      bf16x8 a0 = ldA(l16, kb), a1 = ldA(16 + l16, kb), a2 = ldA(32 + l16, kb), a3 = ldA(48 + l16, kb);
      #pragma unroll
      for (int nt = 0; nt < 2; ++nt) {
        bf16x8 b = *(const bf16x8*)(ws + OFF_WO + (((w * 8 + kk) * 2 + nt) * 64 + lane) * 8);
        o[0][nt] = MFMA16(a0, b, o[0][nt]);
        o[1][nt] = MFMA16(a1, b, o[1][nt]);
        o[2][nt] = MFMA16(a2, b, o[2][nt]);
        o[3][nt] = MFMA16(a3, b, o[3][nt]);
      }
    }
    float* dst = outp + (size_t)blk * 16384;
    #pragma unroll
    for (int mt = 0; mt < 4; ++mt)
      #pragma unroll
      for (int r = 0; r < 4; ++r) {
        int row = mt * 16 + row4 + r;
        #pragma unroll
        for (int nt = 0; nt < 2; ++nt)
          dst[row * 256 + w * 32 + nt * 16 + l16] = o[mt][nt][r] + bov[nt];
      }
  }
}

extern "C" void kernel_launch(void* const* d_in, const int* in_sizes, int n_in,
                              void* d_out, int out_size, void* d_ws, size_t ws_size,
                              hipStream_t stream) {
  const float* query   = (const float*)d_in[0];
  const float* context = (const float*)d_in[1];
  const float* fk      = (const float*)d_in[2];
  const float* fv      = (const float*)d_in[3];
  const float* dk      = (const float*)d_in[4];
  const float* dv      = (const float*)d_in[5];
  const float* Wq      = (const float*)d_in[6];
  const float* bq      = (const float*)d_in[7];
  const float* Wg      = (const float*)d_in[8];
  const float* bg      = (const float*)d_in[9];
  const float* Wc1     = (const float*)d_in[10];
  const float* bc1     = (const float*)d_in[11];
  const float* Wc2     = (const float*)d_in[12];
  const float* bc2     = (const float*)d_in[13];
  const float* Wo      = (const float*)d_in[14];
  const float* bo      = (const float*)d_in[15];
  // d_in[16] Ws, d_in[17] bs: dead code (surprise is deleted)
  const float* mixl    = (const float*)d_in[18];
  u16* ws = (u16*)d_ws;
  float* outp = (float*)d_out;

  k_prep<<<116, 256, 0, stream>>>(Wq, Wg, Wc1, Wo, fk, fv, dk, dv, ws);
  k_fused<<<1024, 512, 0, stream>>>(query, context, bq, bg, bc1, Wc2, bc2, bo,
                                    mixl, ws, outp);
}

// Round 2
// 294.906 us; speedup vs baseline: 1.1081x; 1.0018x over previous
//
#include <hip/hip_runtime.h>

typedef unsigned short u16;
typedef __attribute__((ext_vector_type(8))) short bf16x8;
typedef __attribute__((ext_vector_type(4))) float f32x4;
typedef __attribute__((ext_vector_type(4))) unsigned short u16x4;
typedef __attribute__((ext_vector_type(8))) unsigned short u16x8;

#define MFMA16(a, b, c) __builtin_amdgcn_mfma_f32_16x16x32_bf16((a), (b), (c), 0, 0, 0)

// d_ws layout (u16 element offsets). All operands PRE-PACKED in per-wave
// fragment order so every B-load in k_fused is a wave-contiguous 1KB burst:
//   dense W (256-out): elem (((w*8+kk)*2+nt)*64+lane)*8+j  <- W[w*32+nt*16+l16][kk*32+quad*8+j]
//   Wc1  (128-out):    elem ((w*8+kk)*64+lane)*8+j         <- Wc1[w*16+l16][kk*32+quad*8+j]
//   KN   (per head):   elem (((h*2+kk)*4+nt)*64+lane)*8+j  <- KN[h][nt*16+l16][kk*32+quad*8+j]
//   VT   (per head):   elem (((h*2+kk)*4+nt)*64+lane)*8+j  <- V [h][kk*32+quad*8+j][nt*16+l16]
#define OFF_WQ   0
#define OFF_WG   65536
#define OFF_WC1  131072
#define OFF_WO   163840
#define OFF_KNF  229376
#define OFF_VTF  245760
#define OFF_KND  262144
#define OFF_VTD  278528

__device__ __forceinline__ u16 f2b(float f) {
  union { float f; unsigned u; } v; v.f = f;
  unsigned r = v.u + 0x7fffu + ((v.u >> 16) & 1u);  // RNE fp32->bf16
  return (u16)(r >> 16);
}
__device__ __forceinline__ float fsig(float x) {
  return __builtin_amdgcn_rcpf(1.f + __expf(-x));
}
__device__ __forceinline__ float ftanh(float x) {
  float e = __expf(2.f * x);
  return (e - 1.f) * __builtin_amdgcn_rcpf(e + 1.f);
}
__device__ __forceinline__ float sum16(float v) {
  v += __shfl_xor(v, 1);
  v += __shfl_xor(v, 2);
  v += __shfl_xor(v, 4);
  v += __shfl_xor(v, 8);
  return v;
}

// ---------- single pre-kernel: convert+pack weights, norm/pack keys, transpose/pack vals ----------
__global__ void k_prep(const float* __restrict__ Wq, const float* __restrict__ Wg,
                       const float* __restrict__ Wc1, const float* __restrict__ Wo,
                       const float* __restrict__ fk, const float* __restrict__ fv,
                       const float* __restrict__ dk, const float* __restrict__ dv,
                       u16* __restrict__ ws) {
  const int bid = blockIdx.x, t = threadIdx.x;
  if (bid < 96) {  // Wq/Wg/Wo: 8192 16B-chunks each, 32 blocks each
    const float* W = bid < 32 ? Wq : (bid < 64 ? Wg : Wo);
    const int OFF = bid < 32 ? OFF_WQ : (bid < 64 ? OFF_WG : OFF_WO);
    int c = (bid & 31) * 256 + t;
    int lane = c & 63, nt = (c >> 6) & 1, kk = (c >> 7) & 7, w = c >> 10;
    const float* s = W + (w * 32 + nt * 16 + (lane & 15)) * 256 + kk * 32 + ((lane >> 4) & 3) * 8;
    u16x8 o;
    #pragma unroll
    for (int j = 0; j < 8; ++j) o[j] = f2b(s[j]);
    *(u16x8*)(ws + OFF + c * 8) = o;
  } else if (bid < 112) {  // Wc1: 4096 chunks, 16 blocks
    int c = (bid - 96) * 256 + t;
    int lane = c & 63, kk = (c >> 6) & 7, w = c >> 9;
    const float* s = Wc1 + (w * 16 + (lane & 15)) * 256 + kk * 32 + ((lane >> 4) & 3) * 8;
    u16x8 o;
    #pragma unroll
    for (int j = 0; j < 8; ++j) o[j] = f2b(s[j]);
    *(u16x8*)(ws + OFF_WC1 + c * 8) = o;
  } else {  // keys/vals: 4 structures x 256 rows, 4 blocks
    int idx = (bid - 112) * 256 + t;
    int st = idx >> 8, rowid = idx & 255;
    int h = rowid >> 6, s = rowid & 63;
    if (st < 2) {  // keys: normalize then scatter into packed B-layout
      const float* p = (st == 0 ? fk : dk) + rowid * 64;
      const int OFF = (st == 0) ? OFF_KNF : OFF_KND;
      float ss = 0.f;
      #pragma unroll
      for (int d = 0; d < 64; ++d) { float x = p[d]; ss += x * x; }
      float sc = __builtin_amdgcn_rcpf(__builtin_amdgcn_sqrtf(ss) + 1e-8f);
      int nt = s >> 4, sl = s & 15;
      #pragma unroll
      for (int d = 0; d < 64; ++d) {
        int lane = ((d >> 3) & 3) * 16 + sl;
        ws[OFF + (((h * 2 + (d >> 5)) * 4 + nt) * 64 + lane) * 8 + (d & 7)] = f2b(p[d] * sc);
      }
    } else {  // vals: transpose into packed B-layout
      const float* p = (st == 2 ? fv : dv) + rowid * 64;
      const int OFF = (st == 2) ? OFF_VTF : OFF_VTD;
      int kk = s >> 5, quad = (s >> 3) & 3, j = s & 7;
      #pragma unroll
      for (int d = 0; d < 64; ++d) {
        int lane = quad * 16 + (d & 15);
        ws[OFF + (((h * 2 + kk) * 4 + (d >> 4)) * 64 + lane) * 8 + j] = f2b(p[d]);
      }
    }
  }
}

// ---------- fused main kernel ----------
// 1024 blocks x 512 threads (8 waves); 64 rows/block.
// Dense GEMMs: wave w owns output cols [w*32, w*32+32).
// Attention: wave w owns head h=w>>1, q-rows rh=(w&1)*32 .. rh+31; the two
// tiers run SEQUENTIALLY so their score/PV accumulators never co-live
// (round-1 version co-lived sf+sd+pv+oacc -> ~54 dwords/thread scratch spill,
// visible as +114MB HBM WRITE_SIZE).
__global__ __launch_bounds__(512, 4)
void k_fused(const float* __restrict__ query, const float* __restrict__ context,
             const float* __restrict__ bq, const float* __restrict__ bg,
             const float* __restrict__ bc1, const float* __restrict__ Wc2,
             const float* __restrict__ bc2v, const float* __restrict__ bo,
             const float* __restrict__ mixl, const u16* __restrict__ ws,
             float* __restrict__ outp) {
  __shared__ u16 sX[64 * 256];      // 32 KB: ctx -> query -> (chunks: q,P) -> out_pre
  __shared__ float red_a[8][64];    // gate partials, then q-norm ss partials
  __shared__ float red_c[8][64];    // conf partials
  __shared__ float sA[64];          // conf*mix
  __shared__ float sB[64];          // conf*(1-mix)

  const int t = threadIdx.x;
  const int w = t >> 6;
  const int lane = t & 63;
  const int quad = lane >> 4;
  const int l16 = lane & 15;
  const int row4 = quad * 4;
  const int h = w >> 1;             // attention head
  const int rh = (w & 1) * 32;      // attention row-half
  const int blk = blockIdx.x;
  char* Xb = (char*)sX;
  char* Ch = Xb + h * 8192;         // per-head 64x64 bf16 chunk (q then P), swizzled

  auto stage = [&](const float* src) {
    #pragma unroll
    for (int i = 0; i < 8; ++i) {
      int e = i * 2048 + t * 4;
      float4 v = *(const float4*)(src + e);
      int row = e >> 8, col = e & 255;
      u16x4 pk;
      pk.x = f2b(v.x); pk.y = f2b(v.y); pk.z = f2b(v.z); pk.w = f2b(v.w);
      *(u16x4*)(Xb + row * 512 + ((((col >> 3) ^ (row & 7)) << 4) | ((col & 7) << 1))) = pk;
    }
  };
  auto ldA = [&](int row, int kb) {  // A-frag from X: m=row, k=kb..kb+7
    return *(const bf16x8*)(Xb + row * 512 + ((((kb >> 3) ^ (row & 7)) << 4)));
  };
  auto ldC = [&](int row, int kb) {  // A-frag from head chunk
    return *(const bf16x8*)(Ch + row * 128 + ((((kb >> 3) ^ (row & 7)) << 4)));
  };
  auto cwr = [&](int row, int col, u16 v) {  // scalar bf16 write into head chunk
    *(u16*)(Ch + row * 128 + (((((col >> 3) ^ (row & 7)) << 3) | (col & 7)) << 1)) = v;
  };

  const f32x4 vzero = {0.f, 0.f, 0.f, 0.f};

  // ===== Phase 1: stage context; hoist small params =====
  stage(context + (size_t)blk * 16384);
  float bgv[2], bqv[2], bov[2];
  #pragma unroll
  for (int nt = 0; nt < 2; ++nt) {
    int n = w * 32 + nt * 16 + l16;
    bgv[nt] = bg[n]; bqv[nt] = bq[n]; bov[nt] = bo[n];
  }
  float bc1v = bc1[w * 16 + l16];
  float wc2v = Wc2[w * 16 + l16];
  __syncthreads();  // bar1: ctx staged

  // ===== gate + conf GEMMs (shared A-frags) =====
  {
    f32x4 ag[4][2], ac[4];
    #pragma unroll
    for (int mt = 0; mt < 4; ++mt) { ag[mt][0] = vzero; ag[mt][1] = vzero; ac[mt] = vzero; }
    #pragma unroll
    for (int kk = 0; kk < 8; ++kk) {
      int kb = kk * 32 + quad * 8;
      bf16x8 a0 = ldA(l16, kb), a1 = ldA(16 + l16, kb), a2 = ldA(32 + l16, kb), a3 = ldA(48 + l16, kb);
      #pragma unroll
      for (int nt = 0; nt < 2; ++nt) {
        bf16x8 b = *(const bf16x8*)(ws + OFF_WG + (((w * 8 + kk) * 2 + nt) * 64 + lane) * 8);
        ag[0][nt] = MFMA16(a0, b, ag[0][nt]);
        ag[1][nt] = MFMA16(a1, b, ag[1][nt]);
        ag[2][nt] = MFMA16(a2, b, ag[2][nt]);
        ag[3][nt] = MFMA16(a3, b, ag[3][nt]);
      }
      bf16x8 bc = *(const bf16x8*)(ws + OFF_WC1 + ((w * 8 + kk) * 64 + lane) * 8);
      ac[0] = MFMA16(a0, bc, ac[0]);
      ac[1] = MFMA16(a1, bc, ac[1]);
      ac[2] = MFMA16(a2, bc, ac[2]);
      ac[3] = MFMA16(a3, bc, ac[3]);
    }
    #pragma unroll
    for (int mt = 0; mt < 4; ++mt)
      #pragma unroll
      for (int r = 0; r < 4; ++r) {
        float sg = ftanh(ag[mt][0][r] + bgv[0]) + ftanh(ag[mt][1][r] + bgv[1]);
        sg = sum16(sg);
        float sc = ftanh(ac[mt][r] + bc1v) * wc2v;
        sc = sum16(sc);
        if (l16 == 0) { red_a[w][mt * 16 + row4 + r] = sg; red_c[w][mt * 16 + row4 + r] = sc; }
      }
  }
  __syncthreads();  // bar2: partials ready, X reads done

  // ===== combine partials; stage query (overwrites X) =====
  if (t < 64) {
    float g = 0.f, cc = 0.f;
    #pragma unroll
    for (int i = 0; i < 8; ++i) { g += red_a[i][t]; cc += red_c[i][t]; }
    float mix = fsig(mixl[0] + g * (1.f / 256.f));
    float conf = fsig(cc + bc2v[0]);
    sA[t] = conf * mix;
    sB[t] = conf - conf * mix;
  }
  stage(query + (size_t)blk * 16384);
  __syncthreads();  // bar3: query staged + sA/sB ready

  // ===== Wq GEMM + per-head q-norm partials =====
  f32x4 qa[4][2];
  {
    #pragma unroll
    for (int mt = 0; mt < 4; ++mt) { qa[mt][0] = vzero; qa[mt][1] = vzero; }
    #pragma unroll
    for (int kk = 0; kk < 8; ++kk) {
      int kb = kk * 32 + quad * 8;
      bf16x8 a0 = ldA(l16, kb), a1 = ldA(16 + l16, kb), a2 = ldA(32 + l16, kb), a3 = ldA(48 + l16, kb);
      #pragma unroll
      for (int nt = 0; nt < 2; ++nt) {
        bf16x8 b = *(const bf16x8*)(ws + OFF_WQ + (((w * 8 + kk) * 2 + nt) * 64 + lane) * 8);
        qa[0][nt] = MFMA16(a0, b, qa[0][nt]);
        qa[1][nt] = MFMA16(a1, b, qa[1][nt]);
        qa[2][nt] = MFMA16(a2, b, qa[2][nt]);
        qa[3][nt] = MFMA16(a3, b, qa[3][nt]);
      }
    }
    #pragma unroll
    for (int mt = 0; mt < 4; ++mt)
      #pragma unroll
      for (int r = 0; r < 4; ++r) {
        float ss = 0.f;
        #pragma unroll
        for (int nt = 0; nt < 2; ++nt) {
          float q_ = qa[mt][nt][r] + bqv[nt];
          qa[mt][nt][r] = q_;
          ss += q_ * q_;
        }
        ss = sum16(ss);
        if (l16 == 0) red_a[w][mt * 16 + row4 + r] = ss;
      }
  }
  __syncthreads();  // bar4: ss partials ready, all X reads done (chunks may overwrite X)

  // write normalized q (bf16) into head chunk: wave w fills d-cols (w&1)*32..+31, all 64 rows
  #pragma unroll
  for (int mt = 0; mt < 4; ++mt)
    #pragma unroll
    for (int r = 0; r < 4; ++r) {
      int row = mt * 16 + row4 + r;
      float ss = red_a[w][row] + red_a[w ^ 1][row];
      float scl = __builtin_amdgcn_rcpf(__builtin_amdgcn_sqrtf(ss) + 1e-8f);
      #pragma unroll
      for (int nt = 0; nt < 2; ++nt)
        cwr(row, (w & 1) * 32 + nt * 16 + l16, f2b(qa[mt][nt][r] * scl));
    }
  __syncthreads();  // bar5: both waves of each head done writing q

  // ===== attention: wave-local from here (no barriers), tiers SEQUENTIAL =====
  bf16x8 qf[2][2];  // q A-frags held in regs across both tiers
  #pragma unroll
  for (int mt = 0; mt < 2; ++mt)
    #pragma unroll
    for (int kk = 0; kk < 2; ++kk)
      qf[mt][kk] = ldC(rh + mt * 16 + l16, kk * 32 + quad * 8);

  f32x4 oacc[2][4];

  #pragma unroll
  for (int tier = 0; tier < 2; ++tier) {
    const u16* KN = ws + (tier == 0 ? OFF_KNF : OFF_KND);
    const u16* VT = ws + (tier == 0 ? OFF_VTF : OFF_VTD);

    // QK^T (cos sims, bounded by 1 -> no max subtraction needed)
    f32x4 s[2][4];
    #pragma unroll
    for (int mt = 0; mt < 2; ++mt)
      #pragma unroll
      for (int nt = 0; nt < 4; ++nt) s[mt][nt] = vzero;
    #pragma unroll
    for (int kk = 0; kk < 2; ++kk)
      #pragma unroll
      for (int nt = 0; nt < 4; ++nt) {
        bf16x8 b = *(const bf16x8*)(KN + (((h * 2 + kk) * 4 + nt) * 64 + lane) * 8);
        s[0][nt] = MFMA16(qf[0][kk], b, s[0][nt]);
        s[1][nt] = MFMA16(qf[1][kk], b, s[1][nt]);
      }

    // softmax -> P (bf16) into head chunk
    #pragma unroll
    for (int mt = 0; mt < 2; ++mt)
      #pragma unroll
      for (int r = 0; r < 4; ++r) {
        float rs = 0.f;
        #pragma unroll
        for (int nt = 0; nt < 4; ++nt) { float e = __expf(s[mt][nt][r]); s[mt][nt][r] = e; rs += e; }
        rs = sum16(rs);
        float inv = __builtin_amdgcn_rcpf(rs);
        int row = rh + mt * 16 + row4 + r;
        #pragma unroll
        for (int nt = 0; nt < 4; ++nt) cwr(row, nt * 16 + l16, f2b(s[mt][nt][r] * inv));
      }

    // PV
    bf16x8 p00 = ldC(rh + l16, quad * 8),      p01 = ldC(rh + l16, 32 + quad * 8);
    bf16x8 p10 = ldC(rh + 16 + l16, quad * 8), p11 = ldC(rh + 16 + l16, 32 + quad * 8);
    f32x4 pv[2][4];
    #pragma unroll
    for (int mt = 0; mt < 2; ++mt)
      #pragma unroll
      for (int nt = 0; nt < 4; ++nt) pv[mt][nt] = vzero;
    #pragma unroll
    for (int kk = 0; kk < 2; ++kk)
      #pragma unroll
      for (int nt = 0; nt < 4; ++nt) {
        bf16x8 b = *(const bf16x8*)(VT + (((h * 2 + kk) * 4 + nt) * 64 + lane) * 8);
        pv[0][nt] = MFMA16(kk ? p01 : p00, b, pv[0][nt]);
        pv[1][nt] = MFMA16(kk ? p11 : p10, b, pv[1][nt]);
      }

    // mix/conf scale; fast tier initializes oacc, deep tier accumulates
    #pragma unroll
    for (int mt = 0; mt < 2; ++mt)
      #pragma unroll
      for (int r = 0; r < 4; ++r) {
        float m_ = (tier == 0) ? sA[rh + mt * 16 + row4 + r] : sB[rh + mt * 16 + row4 + r];
        #pragma unroll
        for (int nt = 0; nt < 4; ++nt) {
          if (tier == 0) oacc[mt][nt][r] = m_ * pv[mt][nt][r];
          else           oacc[mt][nt][r] += m_ * pv[mt][nt][r];
        }
      }
  }

  // ===== Phase 3: out_pre -> X, final GEMM (Wo) =====
  __syncthreads();  // bar6: all chunk reads done before X reused as out_pre
  #pragma unroll
  for (int mt = 0; mt < 2; ++mt)
    #pragma unroll
    for (int r = 0; r < 4; ++r) {
      int row = rh + mt * 16 + row4 + r;
      #pragma unroll
      for (int nt = 0; nt < 4; ++nt) {
        int col = h * 64 + nt * 16 + l16;
        *(u16*)(Xb + row * 512 + ((((col >> 3) ^ (row & 7)) << 4) | ((col & 7) << 1))) =
            f2b(oacc[mt][nt][r]);
      }
    }
  __syncthreads();  // bar7: out_pre complete

  {
    f32x4 o[4][2];
    #pragma unroll
    for (int mt = 0; mt < 4; ++mt) { o[mt][0] = vzero; o[mt][1] = vzero; }
    #pragma unroll
    for (int kk = 0; kk < 8; ++kk) {
      int kb = kk * 32 + quad * 8;
      bf16x8 a0 = ldA(l16, kb), a1 = ldA(16 + l16, kb), a2 = ldA(32 + l16, kb), a3 = ldA(48 + l16, kb);
      #pragma unroll
      for (int nt = 0; nt < 2; ++nt) {
        bf16x8 b = *(const bf16x8*)(ws + OFF_WO + (((w * 8 + kk) * 2 + nt) * 64 + lane) * 8);
        o[0][nt] = MFMA16(a0, b, o[0][nt]);
        o[1][nt] = MFMA16(a1, b, o[1][nt]);
        o[2][nt] = MFMA16(a2, b, o[2][nt]);
        o[3][nt] = MFMA16(a3, b, o[3][nt]);
      }
    }
    float* dst = outp + (size_t)blk * 16384;
    #pragma unroll
    for (int mt = 0; mt < 4; ++mt)
      #pragma unroll
      for (int r = 0; r < 4; ++r) {
        int row = mt * 16 + row4 + r;
        #pragma unroll
        for (int nt = 0; nt < 2; ++nt)
          dst[row * 256 + w * 32 + nt * 16 + l16] = o[mt][nt][r] + bov[nt];
      }
  }
}

extern "C" void kernel_launch(void* const* d_in, const int* in_sizes, int n_in,
                              void* d_out, int out_size, void* d_ws, size_t ws_size,
                              hipStream_t stream) {
  const float* query   = (const float*)d_in[0];
  const float* context = (const float*)d_in[1];
  const float* fk      = (const float*)d_in[2];
  const float* fv      = (const float*)d_in[3];
  const float* dk      = (const float*)d_in[4];
  const float* dv      = (const float*)d_in[5];
  const float* Wq      = (const float*)d_in[6];
  const float* bq      = (const float*)d_in[7];
  const float* Wg      = (const float*)d_in[8];
  const float* bg      = (const float*)d_in[9];
  const float* Wc1     = (const float*)d_in[10];
  const float* bc1     = (const float*)d_in[11];
  const float* Wc2     = (const float*)d_in[12];
  const float* bc2     = (const float*)d_in[13];
  const float* Wo      = (const float*)d_in[14];
  const float* bo      = (const float*)d_in[15];
  // d_in[16] Ws, d_in[17] bs: dead code (surprise is deleted)
  const float* mixl    = (const float*)d_in[18];
  u16* ws = (u16*)d_ws;
  float* outp = (float*)d_out;

  k_prep<<<116, 256, 0, stream>>>(Wq, Wg, Wc1, Wo, fk, fv, dk, dv, ws);
  k_fused<<<1024, 512, 0, stream>>>(query, context, bq, bg, bc1, Wc2, bc2, bo,
                                    mixl, ws, outp);
}

// Round 3
// 281.270 us; speedup vs baseline: 1.1618x; 1.0485x over previous
//
#include <hip/hip_runtime.h>

typedef unsigned short u16;
typedef __attribute__((ext_vector_type(8))) short bf16x8;
typedef __attribute__((ext_vector_type(4))) float f32x4;
typedef __attribute__((ext_vector_type(4))) unsigned short u16x4;
typedef __attribute__((ext_vector_type(8))) unsigned short u16x8;

#define MFMA16(a, b, c) __builtin_amdgcn_mfma_f32_16x16x32_bf16((a), (b), (c), 0, 0, 0)

// d_ws layout (u16 element offsets). All operands PRE-PACKED in per-wave
// fragment order so every B-load in k_fused is a wave-contiguous 1KB burst:
//   dense W (256-out): elem (((w*8+kk)*2+nt)*64+lane)*8+j  <- W[w*32+nt*16+l16][kk*32+quad*8+j]
//   Wc1  (128-out):    elem ((w*8+kk)*64+lane)*8+j         <- Wc1[w*16+l16][kk*32+quad*8+j]
//   KN   (per head):   elem (((h*2+kk)*4+nt)*64+lane)*8+j  <- KN[h][nt*16+l16][kk*32+quad*8+j]
//   VT   (per head):   elem (((h*2+kk)*4+nt)*64+lane)*8+j  <- V [h][kk*32+quad*8+j][nt*16+l16]
#define OFF_WQ   0
#define OFF_WG   65536
#define OFF_WC1  131072
#define OFF_WO   163840
#define OFF_KNF  229376
#define OFF_VTF  245760
#define OFF_KND  262144
#define OFF_VTD  278528

__device__ __forceinline__ u16 f2b(float f) {
  union { float f; unsigned u; } v; v.f = f;
  unsigned r = v.u + 0x7fffu + ((v.u >> 16) & 1u);  // RNE fp32->bf16
  return (u16)(r >> 16);
}
__device__ __forceinline__ unsigned pk2(float lo, float hi) {  // 2x f32 -> packed bf16 (RNE)
  unsigned r;
  asm("v_cvt_pk_bf16_f32 %0, %1, %2" : "=v"(r) : "v"(lo), "v"(hi));
  return r;
}
__device__ __forceinline__ float fsig(float x) {
  return __builtin_amdgcn_rcpf(1.f + __expf(-x));
}
__device__ __forceinline__ float ftanh(float x) {
  float e = __expf(2.f * x);
  return (e - 1.f) * __builtin_amdgcn_rcpf(e + 1.f);
}
__device__ __forceinline__ float sum16(float v) {
  v += __shfl_xor(v, 1);
  v += __shfl_xor(v, 2);
  v += __shfl_xor(v, 4);
  v += __shfl_xor(v, 8);
  return v;
}

// ---------- single pre-kernel: convert+pack weights, norm/pack keys, transpose/pack vals ----------
__global__ void k_prep(const float* __restrict__ Wq, const float* __restrict__ Wg,
                       const float* __restrict__ Wc1, const float* __restrict__ Wo,
                       const float* __restrict__ fk, const float* __restrict__ fv,
                       const float* __restrict__ dk, const float* __restrict__ dv,
                       u16* __restrict__ ws) {
  const int bid = blockIdx.x, t = threadIdx.x;
  if (bid < 96) {  // Wq/Wg/Wo: 8192 16B-chunks each, 32 blocks each
    const float* W = bid < 32 ? Wq : (bid < 64 ? Wg : Wo);
    const int OFF = bid < 32 ? OFF_WQ : (bid < 64 ? OFF_WG : OFF_WO);
    int c = (bid & 31) * 256 + t;
    int lane = c & 63, nt = (c >> 6) & 1, kk = (c >> 7) & 7, w = c >> 10;
    const float* s = W + (w * 32 + nt * 16 + (lane & 15)) * 256 + kk * 32 + ((lane >> 4) & 3) * 8;
    u16x8 o;
    #pragma unroll
    for (int j = 0; j < 8; ++j) o[j] = f2b(s[j]);
    *(u16x8*)(ws + OFF + c * 8) = o;
  } else if (bid < 112) {  // Wc1: 4096 chunks, 16 blocks
    int c = (bid - 96) * 256 + t;
    int lane = c & 63, kk = (c >> 6) & 7, w = c >> 9;
    const float* s = Wc1 + (w * 16 + (lane & 15)) * 256 + kk * 32 + ((lane >> 4) & 3) * 8;
    u16x8 o;
    #pragma unroll
    for (int j = 0; j < 8; ++j) o[j] = f2b(s[j]);
    *(u16x8*)(ws + OFF_WC1 + c * 8) = o;
  } else {  // keys/vals: 4 structures x 256 rows, 4 blocks
    int idx = (bid - 112) * 256 + t;
    int st = idx >> 8, rowid = idx & 255;
    int h = rowid >> 6, s = rowid & 63;
    if (st < 2) {  // keys: normalize then scatter into packed B-layout
      const float* p = (st == 0 ? fk : dk) + rowid * 64;
      const int OFF = (st == 0) ? OFF_KNF : OFF_KND;
      float ss = 0.f;
      #pragma unroll
      for (int d = 0; d < 64; ++d) { float x = p[d]; ss += x * x; }
      float sc = __builtin_amdgcn_rcpf(__builtin_amdgcn_sqrtf(ss) + 1e-8f);
      int nt = s >> 4, sl = s & 15;
      #pragma unroll
      for (int d = 0; d < 64; ++d) {
        int lane = ((d >> 3) & 3) * 16 + sl;
        ws[OFF + (((h * 2 + (d >> 5)) * 4 + nt) * 64 + lane) * 8 + (d & 7)] = f2b(p[d] * sc);
      }
    } else {  // vals: transpose into packed B-layout
      const float* p = (st == 2 ? fv : dv) + rowid * 64;
      const int OFF = (st == 2) ? OFF_VTF : OFF_VTD;
      int kk = s >> 5, quad = (s >> 3) & 3, j = s & 7;
      #pragma unroll
      for (int d = 0; d < 64; ++d) {
        int lane = quad * 16 + (d & 15);
        ws[OFF + (((h * 2 + kk) * 4 + (d >> 4)) * 64 + lane) * 8 + j] = f2b(p[d]);
      }
    }
  }
}

// ---------- fused main kernel ----------
// 1024 blocks x 512 threads (8 waves); 64 rows/block.
// Dense GEMMs: wave w owns output cols [w*32, w*32+32).
// Attention: wave w owns head h=w>>1, q-rows rh=(w&1)*32..+31, processed as
// TWO sequential 16-row halves so per-slice accumulators are f32x4[4] (16
// regs) -> structurally spill-free under the (512,4) 128-reg cap.
// Dual LDS buffers: sX = context -> per-head chunks (q,P);
//                   sY = query   -> out_pre.   Both staged at kernel entry.
__global__ __launch_bounds__(512, 4)
void k_fused(const float* __restrict__ query, const float* __restrict__ context,
             const float* __restrict__ bq, const float* __restrict__ bg,
             const float* __restrict__ bc1, const float* __restrict__ Wc2,
             const float* __restrict__ bc2v, const float* __restrict__ bo,
             const float* __restrict__ mixl, const u16* __restrict__ ws,
             float* __restrict__ outp) {
  __shared__ u16 sX[64 * 256];      // 32 KB: ctx -> head chunks (q,P)
  __shared__ u16 sY[64 * 256];      // 32 KB: query -> out_pre
  __shared__ float red_a[8][64];    // gate partials
  __shared__ float red_c[8][64];    // conf partials
  __shared__ float red_q[8][64];    // q-norm ss partials
  __shared__ float sA[64];          // conf*mix
  __shared__ float sB[64];          // conf*(1-mix)

  const int t = threadIdx.x;
  const int w = t >> 6;
  const int lane = t & 63;
  const int quad = lane >> 4;
  const int l16 = lane & 15;
  const int row4 = quad * 4;
  const int h = w >> 1;             // attention head
  const int rh = (w & 1) * 32;      // attention row-half (32 rows)
  const int blk = blockIdx.x;
  char* Xb = (char*)sX;
  char* Yb = (char*)sY;
  char* Ch = Xb + h * 8192;         // per-head 64x64 bf16 chunk (q then P), swizzled

  auto stage = [&](char* dstB, const float* src) {
    #pragma unroll
    for (int i = 0; i < 8; ++i) {
      int e = i * 2048 + t * 4;
      float4 v = *(const float4*)(src + e);
      int row = e >> 8, col = e & 255;
      uint2 pk;
      pk.x = pk2(v.x, v.y);
      pk.y = pk2(v.z, v.w);
      *(uint2*)(dstB + row * 512 + ((((col >> 3) ^ (row & 7)) << 4) | ((col & 7) << 1))) = pk;
    }
  };
  auto ldA = [&](const char* B, int row, int kb) {  // A-frag: m=row, k=kb..kb+7
    return *(const bf16x8*)(B + row * 512 + ((((kb >> 3) ^ (row & 7)) << 4)));
  };
  auto ldC = [&](int row, int kb) {  // A-frag from head chunk
    return *(const bf16x8*)(Ch + row * 128 + ((((kb >> 3) ^ (row & 7)) << 4)));
  };
  auto cwr = [&](int row, int col, u16 v) {  // scalar bf16 write into head chunk
    *(u16*)(Ch + row * 128 + (((((col >> 3) ^ (row & 7)) << 3) | (col & 7)) << 1)) = v;
  };
  auto ywr = [&](int row, int col, u16 v) {  // scalar bf16 write into sY (out_pre)
    *(u16*)(Yb + row * 512 + (((((col >> 3) ^ (row & 7)) << 3) | (col & 7)) << 1)) = v;
  };

  const f32x4 vzero = {0.f, 0.f, 0.f, 0.f};

  // ===== entry: stage BOTH inputs; hoist small params =====
  stage(Xb, context + (size_t)blk * 16384);
  stage(Yb, query + (size_t)blk * 16384);
  float bgv[2], bqv[2], bov[2];
  #pragma unroll
  for (int nt = 0; nt < 2; ++nt) {
    int n = w * 32 + nt * 16 + l16;
    bgv[nt] = bg[n]; bqv[nt] = bq[n]; bov[nt] = bo[n];
  }
  float bc1v = bc1[w * 16 + l16];
  float wc2v = Wc2[w * 16 + l16];
  __syncthreads();  // bar1: both stages complete

  // ===== gate + conf GEMMs on X (shared A-frags) =====
  {
    f32x4 ag[4][2], ac[4];
    #pragma unroll
    for (int mt = 0; mt < 4; ++mt) { ag[mt][0] = vzero; ag[mt][1] = vzero; ac[mt] = vzero; }
    #pragma unroll
    for (int kk = 0; kk < 8; ++kk) {
      int kb = kk * 32 + quad * 8;
      bf16x8 a0 = ldA(Xb, l16, kb), a1 = ldA(Xb, 16 + l16, kb),
             a2 = ldA(Xb, 32 + l16, kb), a3 = ldA(Xb, 48 + l16, kb);
      #pragma unroll
      for (int nt = 0; nt < 2; ++nt) {
        bf16x8 b = *(const bf16x8*)(ws + OFF_WG + (((w * 8 + kk) * 2 + nt) * 64 + lane) * 8);
        ag[0][nt] = MFMA16(a0, b, ag[0][nt]);
        ag[1][nt] = MFMA16(a1, b, ag[1][nt]);
        ag[2][nt] = MFMA16(a2, b, ag[2][nt]);
        ag[3][nt] = MFMA16(a3, b, ag[3][nt]);
      }
      bf16x8 bc = *(const bf16x8*)(ws + OFF_WC1 + ((w * 8 + kk) * 64 + lane) * 8);
      ac[0] = MFMA16(a0, bc, ac[0]);
      ac[1] = MFMA16(a1, bc, ac[1]);
      ac[2] = MFMA16(a2, bc, ac[2]);
      ac[3] = MFMA16(a3, bc, ac[3]);
    }
    #pragma unroll
    for (int mt = 0; mt < 4; ++mt)
      #pragma unroll
      for (int r = 0; r < 4; ++r) {
        float sg = ftanh(ag[mt][0][r] + bgv[0]) + ftanh(ag[mt][1][r] + bgv[1]);
        sg = sum16(sg);
        float sc = ftanh(ac[mt][r] + bc1v) * wc2v;
        sc = sum16(sc);
        if (l16 == 0) { red_a[w][mt * 16 + row4 + r] = sg; red_c[w][mt * 16 + row4 + r] = sc; }
      }
  }
  __syncthreads();  // bar2: gate/conf partials published; X A-frag reads done

  // ===== Wq GEMM on Y + q-norm partials; wave0 lanes combine mix/conf =====
  if (t < 64) {
    float g = 0.f, cc = 0.f;
    #pragma unroll
    for (int i = 0; i < 8; ++i) { g += red_a[i][t]; cc += red_c[i][t]; }
    float mix = fsig(mixl[0] + g * (1.f / 256.f));
    float conf = fsig(cc + bc2v[0]);
    sA[t] = conf * mix;
    sB[t] = conf - conf * mix;
  }
  f32x4 qa[4][2];
  {
    #pragma unroll
    for (int mt = 0; mt < 4; ++mt) { qa[mt][0] = vzero; qa[mt][1] = vzero; }
    #pragma unroll
    for (int kk = 0; kk < 8; ++kk) {
      int kb = kk * 32 + quad * 8;
      bf16x8 a0 = ldA(Yb, l16, kb), a1 = ldA(Yb, 16 + l16, kb),
             a2 = ldA(Yb, 32 + l16, kb), a3 = ldA(Yb, 48 + l16, kb);
      #pragma unroll
      for (int nt = 0; nt < 2; ++nt) {
        bf16x8 b = *(const bf16x8*)(ws + OFF_WQ + (((w * 8 + kk) * 2 + nt) * 64 + lane) * 8);
        qa[0][nt] = MFMA16(a0, b, qa[0][nt]);
        qa[1][nt] = MFMA16(a1, b, qa[1][nt]);
        qa[2][nt] = MFMA16(a2, b, qa[2][nt]);
        qa[3][nt] = MFMA16(a3, b, qa[3][nt]);
      }
    }
    #pragma unroll
    for (int mt = 0; mt < 4; ++mt)
      #pragma unroll
      for (int r = 0; r < 4; ++r) {
        float ss = 0.f;
        #pragma unroll
        for (int nt = 0; nt < 2; ++nt) {
          float q_ = qa[mt][nt][r] + bqv[nt];
          qa[mt][nt][r] = q_;
          ss += q_ * q_;
        }
        ss = sum16(ss);
        if (l16 == 0) red_q[w][mt * 16 + row4 + r] = ss;
      }
  }
  __syncthreads();  // bar3: red_q + sA/sB published; Y A-frag reads done

  // write normalized q (bf16) into head chunk (overwrites X region; X dead since bar2)
  #pragma unroll
  for (int mt = 0; mt < 4; ++mt)
    #pragma unroll
    for (int r = 0; r < 4; ++r) {
      int row = mt * 16 + row4 + r;
      float ss = red_q[w][row] + red_q[w ^ 1][row];
      float scl = __builtin_amdgcn_rcpf(__builtin_amdgcn_sqrtf(ss) + 1e-8f);
      #pragma unroll
      for (int nt = 0; nt < 2; ++nt)
        cwr(row, (w & 1) * 32 + nt * 16 + l16, f2b(qa[mt][nt][r] * scl));
    }
  __syncthreads();  // bar4: both waves of each head done writing q

  // ===== attention: wave-local, two 16-row halves, tiers sequential =====
  #pragma unroll
  for (int half = 0; half < 2; ++half) {
    const int r0 = rh + half * 16;
    bf16x8 q0 = ldC(r0 + l16, quad * 8);
    bf16x8 q1 = ldC(r0 + l16, 32 + quad * 8);
    f32x4 oa[4];

    #pragma unroll
    for (int tier = 0; tier < 2; ++tier) {
      const u16* KN = ws + (tier == 0 ? OFF_KNF : OFF_KND);
      const u16* VT = ws + (tier == 0 ? OFF_VTF : OFF_VTD);

      // QK^T (cos sims bounded by 1 -> no max subtraction)
      f32x4 s4[4];
      #pragma unroll
      for (int nt = 0; nt < 4; ++nt) s4[nt] = vzero;
      #pragma unroll
      for (int kk = 0; kk < 2; ++kk)
        #pragma unroll
        for (int nt = 0; nt < 4; ++nt) {
          bf16x8 b = *(const bf16x8*)(KN + (((h * 2 + kk) * 4 + nt) * 64 + lane) * 8);
          s4[nt] = MFMA16(kk ? q1 : q0, b, s4[nt]);
        }

      // softmax -> P (bf16) into head chunk
      #pragma unroll
      for (int r = 0; r < 4; ++r) {
        float rs = 0.f;
        #pragma unroll
        for (int nt = 0; nt < 4; ++nt) { float e = __expf(s4[nt][r]); s4[nt][r] = e; rs += e; }
        rs = sum16(rs);
        float inv = __builtin_amdgcn_rcpf(rs);
        int row = r0 + row4 + r;
        #pragma unroll
        for (int nt = 0; nt < 4; ++nt) cwr(row, nt * 16 + l16, f2b(s4[nt][r] * inv));
      }

      // PV
      bf16x8 p0 = ldC(r0 + l16, quad * 8);
      bf16x8 p1 = ldC(r0 + l16, 32 + quad * 8);
      f32x4 pv4[4];
      #pragma unroll
      for (int nt = 0; nt < 4; ++nt) pv4[nt] = vzero;
      #pragma unroll
      for (int kk = 0; kk < 2; ++kk)
        #pragma unroll
        for (int nt = 0; nt < 4; ++nt) {
          bf16x8 b = *(const bf16x8*)(VT + (((h * 2 + kk) * 4 + nt) * 64 + lane) * 8);
          pv4[nt] = MFMA16(kk ? p1 : p0, b, pv4[nt]);
        }

      // mix/conf scale; fast tier initializes oa, deep tier accumulates
      #pragma unroll
      for (int r = 0; r < 4; ++r) {
        int row = r0 + row4 + r;
        float m_ = (tier == 0) ? sA[row] : sB[row];
        #pragma unroll
        for (int nt = 0; nt < 4; ++nt) {
          if (tier == 0) oa[nt][r] = m_ * pv4[nt][r];
          else           oa[nt][r] += m_ * pv4[nt][r];
        }
      }
    }

    // retire this half's out_pre into sY (query dead since bar3)
    #pragma unroll
    for (int r = 0; r < 4; ++r) {
      int row = r0 + row4 + r;
      #pragma unroll
      for (int nt = 0; nt < 4; ++nt)
        ywr(row, h * 64 + nt * 16 + l16, f2b(oa[nt][r]));
    }
  }
  __syncthreads();  // bar5: out_pre complete

  // ===== final GEMM (Wo) on Y =====
  {
    f32x4 o[4][2];
    #pragma unroll
    for (int mt = 0; mt < 4; ++mt) { o[mt][0] = vzero; o[mt][1] = vzero; }
    #pragma unroll
    for (int kk = 0; kk < 8; ++kk) {
      int kb = kk * 32 + quad * 8;
      bf16x8 a0 = ldA(Yb, l16, kb), a1 = ldA(Yb, 16 + l16, kb),
             a2 = ldA(Yb, 32 + l16, kb), a3 = ldA(Yb, 48 + l16, kb);
      #pragma unroll
      for (int nt = 0; nt < 2; ++nt) {
        bf16x8 b = *(const bf16x8*)(ws + OFF_WO + (((w * 8 + kk) * 2 + nt) * 64 + lane) * 8);
        o[0][nt] = MFMA16(a0, b, o[0][nt]);
        o[1][nt] = MFMA16(a1, b, o[1][nt]);
        o[2][nt] = MFMA16(a2, b, o[2][nt]);
        o[3][nt] = MFMA16(a3, b, o[3][nt]);
      }
    }
    float* dst = outp + (size_t)blk * 16384;
    #pragma unroll
    for (int mt = 0; mt < 4; ++mt)
      #pragma unroll
      for (int r = 0; r < 4; ++r) {
        int row = mt * 16 + row4 + r;
        #pragma unroll
        for (int nt = 0; nt < 2; ++nt)
          dst[row * 256 + w * 32 + nt * 16 + l16] = o[mt][nt][r] + bov[nt];
      }
  }
}

extern "C" void kernel_launch(void* const* d_in, const int* in_sizes, int n_in,
                              void* d_out, int out_size, void* d_ws, size_t ws_size,
                              hipStream_t stream) {
  const float* query   = (const float*)d_in[0];
  const float* context = (const float*)d_in[1];
  const float* fk      = (const float*)d_in[2];
  const float* fv      = (const float*)d_in[3];
  const float* dk      = (const float*)d_in[4];
  const float* dv      = (const float*)d_in[5];
  const float* Wq      = (const float*)d_in[6];
  const float* bq      = (const float*)d_in[7];
  const float* Wg      = (const float*)d_in[8];
  const float* bg      = (const float*)d_in[9];
  const float* Wc1     = (const float*)d_in[10];
  const float* bc1     = (const float*)d_in[11];
  const float* Wc2     = (const float*)d_in[12];
  const float* bc2     = (const float*)d_in[13];
  const float* Wo      = (const float*)d_in[14];
  const float* bo      = (const float*)d_in[15];
  // d_in[16] Ws, d_in[17] bs: dead code (surprise is deleted)
  const float* mixl    = (const float*)d_in[18];
  u16* ws = (u16*)d_ws;
  float* outp = (float*)d_out;

  k_prep<<<116, 256, 0, stream>>>(Wq, Wg, Wc1, Wo, fk, fv, dk, dv, ws);
  k_fused<<<1024, 512, 0, stream>>>(query, context, bq, bg, bc1, Wc2, bc2, bo,
                                    mixl, ws, outp);
}

// Round 4
// 276.330 us; speedup vs baseline: 1.1826x; 1.0179x over previous
//
#include <hip/hip_runtime.h>

typedef unsigned short u16;
typedef __attribute__((ext_vector_type(8))) short bf16x8;
typedef __attribute__((ext_vector_type(4))) float f32x4;
typedef __attribute__((ext_vector_type(8))) unsigned short u16x8;

#define MFMA16(a, b, c) __builtin_amdgcn_mfma_f32_16x16x32_bf16((a), (b), (c), 0, 0, 0)

// d_ws layout (u16 element offsets). All operands PRE-PACKED in per-fragment
// order so every B-load in k_fused is a wave-contiguous 1KB burst.
//   dense W: 16-col group g, k-step kk: elem (((g>>1)*8+kk)*2+(g&1))*512 + lane*8 + j
//            <- W[g*16 + (lane&15)][kk*32 + ((lane>>4)&3)*8 + j]
//   Wc1:     elem ((w*8+kk)*512) + lane*8 + j
//   KN/VT (per head h): elem (((h*2+kk)*4+nt)*512) + lane*8 + j
#define OFF_WQ   0
#define OFF_WG   65536
#define OFF_WC1  131072
#define OFF_WO   163840
#define OFF_KNF  229376
#define OFF_VTF  245760
#define OFF_KND  262144
#define OFF_VTD  278528

__device__ __forceinline__ u16 f2b(float f) {
  union { float f; unsigned u; } v; v.f = f;
  unsigned r = v.u + 0x7fffu + ((v.u >> 16) & 1u);  // RNE fp32->bf16
  return (u16)(r >> 16);
}
__device__ __forceinline__ unsigned pk2(float lo, float hi) {  // 2x f32 -> packed bf16 (RNE)
  unsigned r;
  asm("v_cvt_pk_bf16_f32 %0, %1, %2" : "=v"(r) : "v"(lo), "v"(hi));
  return r;
}
__device__ __forceinline__ float fsig(float x) {
  return __builtin_amdgcn_rcpf(1.f + __expf(-x));
}
__device__ __forceinline__ float ftanh(float x) {
  float e = __expf(2.f * x);
  return (e - 1.f) * __builtin_amdgcn_rcpf(e + 1.f);
}
__device__ __forceinline__ float sum16(float v) {
  v += __shfl_xor(v, 1);
  v += __shfl_xor(v, 2);
  v += __shfl_xor(v, 4);
  v += __shfl_xor(v, 8);
  return v;
}

// ---------- pre-kernel: convert+pack weights; norm/pack keys; transpose/pack vals ----------
// blocks 0..95: Wq/Wg/Wo. 96..111: Wc1. 112..367: keys/vals, one WAVE per (structure,row).
__global__ void k_prep(const float* __restrict__ Wq, const float* __restrict__ Wg,
                       const float* __restrict__ Wc1, const float* __restrict__ Wo,
                       const float* __restrict__ fk, const float* __restrict__ fv,
                       const float* __restrict__ dk, const float* __restrict__ dv,
                       u16* __restrict__ ws) {
  const int bid = blockIdx.x, t = threadIdx.x;
  if (bid < 96) {  // Wq/Wg/Wo: 8192 16B-chunks each, 32 blocks each
    const float* W = bid < 32 ? Wq : (bid < 64 ? Wg : Wo);
    const int OFF = bid < 32 ? OFF_WQ : (bid < 64 ? OFF_WG : OFF_WO);
    int c = (bid & 31) * 256 + t;
    int lane = c & 63, nt = (c >> 6) & 1, kk = (c >> 7) & 7, w = c >> 10;
    const float* s = W + (w * 32 + nt * 16 + (lane & 15)) * 256 + kk * 32 + ((lane >> 4) & 3) * 8;
    u16x8 o;
    #pragma unroll
    for (int j = 0; j < 8; ++j) o[j] = f2b(s[j]);
    *(u16x8*)(ws + OFF + c * 8) = o;
  } else if (bid < 112) {  // Wc1: 4096 chunks, 16 blocks
    int c = (bid - 96) * 256 + t;
    int lane = c & 63, kk = (c >> 6) & 7, w = c >> 9;
    const float* s = Wc1 + (w * 16 + (lane & 15)) * 256 + kk * 32 + ((lane >> 4) & 3) * 8;
    u16x8 o;
    #pragma unroll
    for (int j = 0; j < 8; ++j) o[j] = f2b(s[j]);
    *(u16x8*)(ws + OFF_WC1 + c * 8) = o;
  } else {  // keys/vals: 1024 (structure,row) units, one wave each
    int unit = (bid - 112) * 4 + (t >> 6);
    int lane = t & 63;
    int st = unit >> 8, rowid = unit & 255;
    int hh = rowid >> 6, s = rowid & 63;
    if (st < 2) {  // keys: coalesced load, wave-reduce norm, 1 scattered store/lane
      const float* p = (st == 0 ? fk : dk) + rowid * 64;
      float x = p[lane];
      float v = x * x;
      v += __shfl_xor(v, 1);  v += __shfl_xor(v, 2);  v += __shfl_xor(v, 4);
      v += __shfl_xor(v, 8);  v += __shfl_xor(v, 16); v += __shfl_xor(v, 32);
      float sc = __builtin_amdgcn_rcpf(__builtin_amdgcn_sqrtf(v) + 1e-8f);
      int nt = s >> 4, kk = lane >> 5, lo = ((lane >> 3) & 3) * 16 + (s & 15), j = lane & 7;
      ws[(st == 0 ? OFF_KNF : OFF_KND) + (((hh * 2 + kk) * 4 + nt) * 64 + lo) * 8 + j] =
          f2b(x * sc);
    } else {  // vals: transpose scatter, 1 store/lane
      const float* p = (st == 2 ? fv : dv) + rowid * 64;
      int kk = s >> 5, qd = (s >> 3) & 3, j = s & 7;
      int lo = qd * 16 + (lane & 15), nt = lane >> 4;
      ws[(st == 2 ? OFF_VTF : OFF_VTD) + (((hh * 2 + kk) * 4 + nt) * 64 + lo) * 8 + j] =
          f2b(p[lane]);
    }
  }
}

// ---------- fused main kernel ----------
// 1024 blocks x 512 threads (8 waves); 64 rows/block.
// gate/conf + Wo: wave w owns output cols [w*32, w*32+32).
// Wq + attention: wave w owns head hd=w&3, rows rb=(w>>2)*32..+31 -> q-norm is
// fully in-wave, attention chunk is wave-private (4KB), no q handoff barrier.
__global__ __launch_bounds__(512, 4)
void k_fused(const float* __restrict__ query, const float* __restrict__ context,
             const float* __restrict__ bq, const float* __restrict__ bg,
             const float* __restrict__ bc1, const float* __restrict__ Wc2,
             const float* __restrict__ bc2v, const float* __restrict__ bo,
             const float* __restrict__ mixl, const u16* __restrict__ ws,
             float* __restrict__ outp) {
  __shared__ u16 sX[64 * 256];      // 32 KB: ctx -> 8 wave-private 32x64 chunks (q,P)
  __shared__ u16 sY[64 * 256];      // 32 KB: query -> out_pre
  __shared__ float red_a[8][64];    // gate partials
  __shared__ float red_c[8][64];    // conf partials
  __shared__ float sA[64];          // conf*mix
  __shared__ float sB[64];          // conf*(1-mix)

  const int t = threadIdx.x;
  const int w = t >> 6;
  const int lane = t & 63;
  const int quad = lane >> 4;
  const int l16 = lane & 15;
  const int row4 = quad * 4;
  const int l16e = l16 & ~1;
  const int oddl = lane & 1;
  const int hd = w & 3;             // attention head (wave-private)
  const int rb = (w >> 2) * 32;     // attention row base
  const int blk = blockIdx.x;
  char* Xb = (char*)sX;
  char* Yb = (char*)sY;
  char* Ch = Xb + w * 4096;         // wave-private 32x64 bf16 chunk, swizzled

  auto stage = [&](char* dstB, const float* src) {
    #pragma unroll
    for (int i = 0; i < 8; ++i) {
      int e = i * 2048 + t * 4;
      float4 v = *(const float4*)(src + e);
      int row = e >> 8, col = e & 255;
      uint2 pk;
      pk.x = pk2(v.x, v.y);
      pk.y = pk2(v.z, v.w);
      *(uint2*)(dstB + row * 512 + ((((col >> 3) ^ (row & 7)) << 4) | ((col & 7) << 1))) = pk;
    }
  };
  auto ldA = [&](const char* B, int row, int kb) {  // A-frag: m=row, k=kb..kb+7
    return *(const bf16x8*)(B + row * 512 + ((((kb >> 3) ^ (row & 7)) << 4)));
  };
  auto ldCh = [&](int row, int kb) {  // A-frag from wave-private chunk (32 rows)
    return *(const bf16x8*)(Ch + row * 128 + ((((kb >> 3) ^ (row & 7)) << 4)));
  };
  // packed pair-lane b32 write of 4 values at cols {nt*16+l16}, nt=0..3
  auto st4c = [&](int row, float v0, float v1, float v2, float v3) {
    float o0 = __shfl_xor(v0, 1), o1 = __shfl_xor(v1, 1);
    float o2 = __shfl_xor(v2, 1), o3 = __shfl_xor(v3, 1);
    float lo0 = oddl ? o1 : v0, hi0 = oddl ? v1 : o0;
    float lo1 = oddl ? o3 : v2, hi1 = oddl ? v3 : o2;
    int c0 = (oddl ? 16 : 0) + l16e, c1 = (oddl ? 48 : 32) + l16e;
    *(unsigned*)(Ch + row * 128 + ((((c0 >> 3) ^ (row & 7)) << 4) | ((c0 & 7) << 1))) = pk2(lo0, hi0);
    *(unsigned*)(Ch + row * 128 + ((((c1 >> 3) ^ (row & 7)) << 4) | ((c1 & 7) << 1))) = pk2(lo1, hi1);
  };
  auto st4y = [&](int row, int cb, float v0, float v1, float v2, float v3) {
    float o0 = __shfl_xor(v0, 1), o1 = __shfl_xor(v1, 1);
    float o2 = __shfl_xor(v2, 1), o3 = __shfl_xor(v3, 1);
    float lo0 = oddl ? o1 : v0, hi0 = oddl ? v1 : o0;
    float lo1 = oddl ? o3 : v2, hi1 = oddl ? v3 : o2;
    int c0 = cb + (oddl ? 16 : 0) + l16e, c1 = cb + (oddl ? 48 : 32) + l16e;
    *(unsigned*)(Yb + row * 512 + ((((c0 >> 3) ^ (row & 7)) << 4) | ((c0 & 7) << 1))) = pk2(lo0, hi0);
    *(unsigned*)(Yb + row * 512 + ((((c1 >> 3) ^ (row & 7)) << 4) | ((c1 & 7) << 1))) = pk2(lo1, hi1);
  };

  const f32x4 vzero = {0.f, 0.f, 0.f, 0.f};

  // ===== entry: prefetch gate kk=0 B-frags (land during staging) =====
  bf16x8 pg0 = *(const bf16x8*)(ws + OFF_WG + ((w * 16 + 0) * 64 + lane) * 8);
  bf16x8 pg1 = *(const bf16x8*)(ws + OFF_WG + ((w * 16 + 1) * 64 + lane) * 8);
  bf16x8 pc0 = *(const bf16x8*)(ws + OFF_WC1 + ((w * 8) * 64 + lane) * 8);

  stage(Xb, context + (size_t)blk * 16384);
  stage(Yb, query + (size_t)blk * 16384);
  float bgv[2], bov[2], bq4[4];
  #pragma unroll
  for (int nt = 0; nt < 2; ++nt) {
    int n = w * 32 + nt * 16 + l16;
    bgv[nt] = bg[n]; bov[nt] = bo[n];
  }
  #pragma unroll
  for (int nt = 0; nt < 4; ++nt) bq4[nt] = bq[hd * 64 + nt * 16 + l16];
  float bc1v = bc1[w * 16 + l16];
  float wc2v = Wc2[w * 16 + l16];
  __syncthreads();  // bar1: both stages complete

  // ===== gate + conf GEMMs on X (shared A-frags) =====
  bf16x8 pq0, pq1;  // Wq kk=0 prefetch (issued after gate MFMA loop)
  {
    f32x4 ag[4][2], ac[4];
    #pragma unroll
    for (int mt = 0; mt < 4; ++mt) { ag[mt][0] = vzero; ag[mt][1] = vzero; ac[mt] = vzero; }
    #pragma unroll
    for (int kk = 0; kk < 8; ++kk) {
      int kb = kk * 32 + quad * 8;
      bf16x8 a0 = ldA(Xb, l16, kb), a1 = ldA(Xb, 16 + l16, kb),
             a2 = ldA(Xb, 32 + l16, kb), a3 = ldA(Xb, 48 + l16, kb);
      bf16x8 b0 = kk ? *(const bf16x8*)(ws + OFF_WG + (((w * 8 + kk) * 2 + 0) * 64 + lane) * 8) : pg0;
      bf16x8 b1 = kk ? *(const bf16x8*)(ws + OFF_WG + (((w * 8 + kk) * 2 + 1) * 64 + lane) * 8) : pg1;
      bf16x8 bc = kk ? *(const bf16x8*)(ws + OFF_WC1 + ((w * 8 + kk) * 64 + lane) * 8) : pc0;
      ag[0][0] = MFMA16(a0, b0, ag[0][0]); ag[0][1] = MFMA16(a0, b1, ag[0][1]);
      ag[1][0] = MFMA16(a1, b0, ag[1][0]); ag[1][1] = MFMA16(a1, b1, ag[1][1]);
      ag[2][0] = MFMA16(a2, b0, ag[2][0]); ag[2][1] = MFMA16(a2, b1, ag[2][1]);
      ag[3][0] = MFMA16(a3, b0, ag[3][0]); ag[3][1] = MFMA16(a3, b1, ag[3][1]);
      ac[0] = MFMA16(a0, bc, ac[0]);
      ac[1] = MFMA16(a1, bc, ac[1]);
      ac[2] = MFMA16(a2, bc, ac[2]);
      ac[3] = MFMA16(a3, bc, ac[3]);
    }
    // prefetch Wq kk=0 (nt 0,1) so the post-bar2 loop starts hot
    pq0 = *(const bf16x8*)(ws + OFF_WQ + ((((hd * 4) >> 1) * 8 * 2 + ((hd * 4) & 1)) * 64 + lane) * 8);
    pq1 = *(const bf16x8*)(ws + OFF_WQ + (((((hd * 4 + 1) >> 1) * 8) * 2 + ((hd * 4 + 1) & 1)) * 64 + lane) * 8);
    #pragma unroll
    for (int mt = 0; mt < 4; ++mt)
      #pragma unroll
      for (int r = 0; r < 4; ++r) {
        float sg = ftanh(ag[mt][0][r] + bgv[0]) + ftanh(ag[mt][1][r] + bgv[1]);
        sg = sum16(sg);
        float sc = ftanh(ac[mt][r] + bc1v) * wc2v;
        sc = sum16(sc);
        if (l16 == 0) { red_a[w][mt * 16 + row4 + r] = sg; red_c[w][mt * 16 + row4 + r] = sc; }
      }
  }
  __syncthreads();  // bar2: partials published; X A-frag reads done (chunks may be written)

  // ===== wave0 combines mix/conf; all waves: Wq GEMM on Y (rows rb..rb+31, head hd) =====
  if (t < 64) {
    float g = 0.f, cc = 0.f;
    #pragma unroll
    for (int i = 0; i < 8; ++i) { g += red_a[i][t]; cc += red_c[i][t]; }
    float mix = fsig(mixl[0] + g * (1.f / 256.f));
    float conf = fsig(cc + bc2v[0]);
    sA[t] = conf * mix;
    sB[t] = conf - conf * mix;
  }
  {
    f32x4 qa[2][4];
    #pragma unroll
    for (int mt = 0; mt < 2; ++mt)
      #pragma unroll
      for (int nt = 0; nt < 4; ++nt) qa[mt][nt] = vzero;
    #pragma unroll
    for (int kk = 0; kk < 8; ++kk) {
      int kb = kk * 32 + quad * 8;
      bf16x8 a0 = ldA(Yb, rb + l16, kb), a1 = ldA(Yb, rb + 16 + l16, kb);
      #pragma unroll
      for (int nt = 0; nt < 4; ++nt) {
        int g = hd * 4 + nt;
        bf16x8 b = (kk == 0 && nt == 0) ? pq0
                 : (kk == 0 && nt == 1) ? pq1
                 : *(const bf16x8*)(ws + OFF_WQ + ((((g >> 1) * 8 + kk) * 2 + (g & 1)) * 64 + lane) * 8);
        qa[0][nt] = MFMA16(a0, b, qa[0][nt]);
        qa[1][nt] = MFMA16(a1, b, qa[1][nt]);
      }
    }
    // in-wave per-head q-norm + packed q write into wave-private chunk
    #pragma unroll
    for (int mt = 0; mt < 2; ++mt)
      #pragma unroll
      for (int r = 0; r < 4; ++r) {
        float ss = 0.f;
        #pragma unroll
        for (int nt = 0; nt < 4; ++nt) {
          float q_ = qa[mt][nt][r] + bq4[nt];
          qa[mt][nt][r] = q_;
          ss += q_ * q_;
        }
        ss = sum16(ss);
        float scl = __builtin_amdgcn_rcpf(__builtin_amdgcn_sqrtf(ss) + 1e-8f);
        st4c(mt * 16 + row4 + r,
             qa[mt][0][r] * scl, qa[mt][1][r] * scl, qa[mt][2][r] * scl, qa[mt][3][r] * scl);
      }
  }
  __syncthreads();  // bar3: Y A-frag reads done (out_pre writable); sA/sB ready

  // ===== attention: fully wave-local, two 16-row halves, tiers sequential =====
  #pragma unroll
  for (int half = 0; half < 2; ++half) {
    const int rl = half * 16;
    bf16x8 q0 = ldCh(rl + l16, quad * 8);
    bf16x8 q1 = ldCh(rl + l16, 32 + quad * 8);
    f32x4 oa[4];

    #pragma unroll
    for (int tier = 0; tier < 2; ++tier) {
      const u16* KN = ws + (tier == 0 ? OFF_KNF : OFF_KND);
      const u16* VT = ws + (tier == 0 ? OFF_VTF : OFF_VTD);

      // QK^T (cos sims bounded by 1 -> no max subtraction)
      f32x4 s4[4];
      #pragma unroll
      for (int nt = 0; nt < 4; ++nt) s4[nt] = vzero;
      #pragma unroll
      for (int kk = 0; kk < 2; ++kk)
        #pragma unroll
        for (int nt = 0; nt < 4; ++nt) {
          bf16x8 b = *(const bf16x8*)(KN + (((hd * 2 + kk) * 4 + nt) * 64 + lane) * 8);
          s4[nt] = MFMA16(kk ? q1 : q0, b, s4[nt]);
        }

      // softmax -> packed P (bf16) into chunk (overwrites q rows; q held in regs)
      #pragma unroll
      for (int r = 0; r < 4; ++r) {
        float rs = 0.f;
        #pragma unroll
        for (int nt = 0; nt < 4; ++nt) { float e = __expf(s4[nt][r]); s4[nt][r] = e; rs += e; }
        rs = sum16(rs);
        float inv = __builtin_amdgcn_rcpf(rs);
        st4c(rl + row4 + r,
             s4[0][r] * inv, s4[1][r] * inv, s4[2][r] * inv, s4[3][r] * inv);
      }

      // PV
      bf16x8 p0 = ldCh(rl + l16, quad * 8);
      bf16x8 p1 = ldCh(rl + l16, 32 + quad * 8);
      f32x4 pv4[4];
      #pragma unroll
      for (int nt = 0; nt < 4; ++nt) pv4[nt] = vzero;
      #pragma unroll
      for (int kk = 0; kk < 2; ++kk)
        #pragma unroll
        for (int nt = 0; nt < 4; ++nt) {
          bf16x8 b = *(const bf16x8*)(VT + (((hd * 2 + kk) * 4 + nt) * 64 + lane) * 8);
          pv4[nt] = MFMA16(kk ? p1 : p0, b, pv4[nt]);
        }

      // mix/conf scale; fast tier initializes oa, deep tier accumulates
      #pragma unroll
      for (int r = 0; r < 4; ++r) {
        int rg = rb + rl + row4 + r;
        float m_ = (tier == 0) ? sA[rg] : sB[rg];
        #pragma unroll
        for (int nt = 0; nt < 4; ++nt) {
          if (tier == 0) oa[nt][r] = m_ * pv4[nt][r];
          else           oa[nt][r] += m_ * pv4[nt][r];
        }
      }
    }

    // retire this half's out_pre into sY (packed writes)
    #pragma unroll
    for (int r = 0; r < 4; ++r)
      st4y(rb + rl + row4 + r, hd * 64, oa[0][r], oa[1][r], oa[2][r], oa[3][r]);
  }

  // prefetch Wo kk=0 B-frags across the barrier
  bf16x8 po0 = *(const bf16x8*)(ws + OFF_WO + (((w * 8) * 2 + 0) * 64 + lane) * 8);
  bf16x8 po1 = *(const bf16x8*)(ws + OFF_WO + (((w * 8) * 2 + 1) * 64 + lane) * 8);
  __syncthreads();  // bar4: out_pre complete

  // ===== final GEMM (Wo) on Y =====
  {
    f32x4 o[4][2];
    #pragma unroll
    for (int mt = 0; mt < 4; ++mt) { o[mt][0] = vzero; o[mt][1] = vzero; }
    #pragma unroll
    for (int kk = 0; kk < 8; ++kk) {
      int kb = kk * 32 + quad * 8;
      bf16x8 a0 = ldA(Yb, l16, kb), a1 = ldA(Yb, 16 + l16, kb),
             a2 = ldA(Yb, 32 + l16, kb), a3 = ldA(Yb, 48 + l16, kb);
      #pragma unroll
      for (int nt = 0; nt < 2; ++nt) {
        bf16x8 b = (kk == 0 && nt == 0) ? po0
                 : (kk == 0 && nt == 1) ? po1
                 : *(const bf16x8*)(ws + OFF_WO + (((w * 8 + kk) * 2 + nt) * 64 + lane) * 8);
        o[0][nt] = MFMA16(a0, b, o[0][nt]);
        o[1][nt] = MFMA16(a1, b, o[1][nt]);
        o[2][nt] = MFMA16(a2, b, o[2][nt]);
        o[3][nt] = MFMA16(a3, b, o[3][nt]);
      }
    }
    float* dst = outp + (size_t)blk * 16384;
    #pragma unroll
    for (int mt = 0; mt < 4; ++mt)
      #pragma unroll
      for (int r = 0; r < 4; ++r) {
        int row = mt * 16 + row4 + r;
        #pragma unroll
        for (int nt = 0; nt < 2; ++nt)
          dst[row * 256 + w * 32 + nt * 16 + l16] = o[mt][nt][r] + bov[nt];
      }
  }
}

extern "C" void kernel_launch(void* const* d_in, const int* in_sizes, int n_in,
                              void* d_out, int out_size, void* d_ws, size_t ws_size,
                              hipStream_t stream) {
  const float* query   = (const float*)d_in[0];
  const float* context = (const float*)d_in[1];
  const float* fk      = (const float*)d_in[2];
  const float* fv      = (const float*)d_in[3];
  const float* dk      = (const float*)d_in[4];
  const float* dv      = (const float*)d_in[5];
  const float* Wq      = (const float*)d_in[6];
  const float* bq      = (const float*)d_in[7];
  const float* Wg      = (const float*)d_in[8];
  const float* bg      = (const float*)d_in[9];
  const float* Wc1     = (const float*)d_in[10];
  const float* bc1     = (const float*)d_in[11];
  const float* Wc2     = (const float*)d_in[12];
  const float* bc2     = (const float*)d_in[13];
  const float* Wo      = (const float*)d_in[14];
  const float* bo      = (const float*)d_in[15];
  // d_in[16] Ws, d_in[17] bs: dead code (surprise is deleted)
  const float* mixl    = (const float*)d_in[18];
  u16* ws = (u16*)d_ws;
  float* outp = (float*)d_out;

  k_prep<<<368, 256, 0, stream>>>(Wq, Wg, Wc1, Wo, fk, fv, dk, dv, ws);
  k_fused<<<1024, 512, 0, stream>>>(query, context, bq, bg, bc1, Wc2, bc2, bo,
                                    mixl, ws, outp);
}